// Round 1
// baseline (3169.948 us; speedup 1.0000x reference)
//
#include <hip/hip_runtime.h>
#include <math.h>

#define NPTS 2048
#define NB 8
// total rows per iteration: 4 mats * 8 batches * 2048 = 65536

// ---------------------------------------------------------------------------
// init: build packed point records (x,y,z, 0.5*|p|^2), zero potentials buf0,
// zero the output scalar. ws is re-poisoned before every timed call, so this
// must run every kernel_launch.
// ---------------------------------------------------------------------------
__global__ __launch_bounds__(256) void emd_init(const float* __restrict__ x,
                                                const float* __restrict__ y,
                                                float4* __restrict__ x4,
                                                float4* __restrict__ y4,
                                                float* __restrict__ pot0,
                                                float* __restrict__ out) {
  int t = blockIdx.x * blockDim.x + threadIdx.x;  // 0..65535
  if (t < NB * NPTS) {
    float a0 = x[3 * t], a1 = x[3 * t + 1], a2 = x[3 * t + 2];
    x4[t] = make_float4(a0, a1, a2, 0.5f * (a0 * a0 + a1 * a1 + a2 * a2));
    float b0 = y[3 * t], b1 = y[3 * t + 1], b2 = y[3 * t + 2];
    y4[t] = make_float4(b0, b1, b2, 0.5f * (b0 * b0 + b1 * b1 + b2 * b2));
  }
  pot0[t] = 0.0f;  // grid exactly covers 4*NB*NPTS
  if (t == 0) out[0] = 0.0f;
}

// ---------------------------------------------------------------------------
// One Sinkhorn softmin sweep over all 4 matrices.
//   mat 0: rows=x cols=y h=g   -> f_new = 0.5*(f + softmin)
//   mat 1: rows=y cols=x h=f   -> g_new
//   mat 2: rows=x cols=x h=fx  -> fx_new
//   mat 3: rows=y cols=y h=gy  -> gy_new
// softmin_i = 0.5|x_i|^2 - eps*ln2*(M + log2 L) + eps*logM, where (M,L) is the
// online base-2 LSE of s_j = ((h_j - 0.5|y_j|^2) + x_i . y_j) * (log2e/eps).
// lane = row, column record broadcast from LDS (wave-uniform address).
// FINAL: instead of updating potentials, accumulate the signed mean into out.
// ---------------------------------------------------------------------------
template <bool FINAL>
__global__ __launch_bounds__(256) void emd_sweep(const float4* __restrict__ x4,
                                                 const float4* __restrict__ y4,
                                                 const float* __restrict__ pot_in,
                                                 float* __restrict__ pot_out,
                                                 float* __restrict__ out,
                                                 float c,            // log2e/eps
                                                 float neg_eps_ln2,  // -eps*ln2
                                                 float eps_logM) {   // eps*log(2048)
  __shared__ float4 colpack[NPTS];      // 32 KB
  __shared__ float mbuf[4][64];
  __shared__ float lbuf[4][64];

  int blk = blockIdx.x;                 // 0..1023
  int mat = blk >> 8;
  int b = (blk >> 5) & 7;
  int ib = blk & 31;
  int tid = threadIdx.x;
  int lane = tid & 63;
  int w = tid >> 6;

  const float4* rowp = (mat == 1 || mat == 3) ? y4 : x4;
  const float4* colp = (mat == 0 || mat == 3) ? y4 : x4;
  int hidx = (mat < 2) ? (mat ^ 1) : mat;
  const float* h = pot_in + (hidx * NB + b) * NPTS;
  const float4* colb = colp + b * NPTS;

  // stage columns: (y0,y1,y2, (h_j - 0.5|y_j|^2) * c)
  for (int j = tid; j < NPTS; j += 256) {
    float4 q = colb[j];
    colpack[j] = make_float4(q.x, q.y, q.z, (h[j] - q.w) * c);
  }
  __syncthreads();

  int i = ib * 64 + lane;
  float4 p = rowp[b * NPTS + i];
  float xs0 = p.x * c, xs1 = p.y * c, xs2 = p.z * c;

  float m = -INFINITY, l = 0.0f;
  int j0 = w * 512;
  for (int jt = 0; jt < 512; jt += 8) {
    float s[8];
#pragma unroll
    for (int k = 0; k < 8; ++k) {
      float4 q = colpack[j0 + jt + k];
      s[k] = fmaf(xs0, q.x, fmaf(xs1, q.y, fmaf(xs2, q.z, q.w)));
    }
    // pairwise max tree for ILP
    float m01 = fmaxf(s[0], s[1]), m23 = fmaxf(s[2], s[3]);
    float m45 = fmaxf(s[4], s[5]), m67 = fmaxf(s[6], s[7]);
    float mt = fmaxf(fmaxf(m01, m23), fmaxf(m45, m67));
    float mn = fmaxf(m, mt);
    float acc = 0.0f;
#pragma unroll
    for (int k = 0; k < 8; ++k) acc += exp2f(s[k] - mn);
    l = fmaf(l, exp2f(m - mn), acc);
    m = mn;
  }
  mbuf[w][lane] = m;
  lbuf[w][lane] = l;
  __syncthreads();

  if (w == 0) {
    float M = mbuf[0][lane];
#pragma unroll
    for (int q = 1; q < 4; ++q) M = fmaxf(M, mbuf[q][lane]);
    float L = 0.0f;
#pragma unroll
    for (int q = 0; q < 4; ++q) L += lbuf[q][lane] * exp2f(mbuf[q][lane] - M);
    float res = p.w + neg_eps_ln2 * (M + log2f(L)) + eps_logM;
    if (FINAL) {
      float sign = (mat < 2) ? 1.0f : -1.0f;
      float val = sign * res * (1.0f / (float)(NB * NPTS));
#pragma unroll
      for (int off = 32; off; off >>= 1) val += __shfl_xor(val, off);
      if (lane == 0) atomicAdd(out, val);
    } else {
      const float* oldp = pot_in + (mat * NB + b) * NPTS;
      float* outp = pot_out + (mat * NB + b) * NPTS;
      outp[i] = 0.5f * (oldp[i] + res);
    }
  }
}

// ---------------------------------------------------------------------------
extern "C" void kernel_launch(void* const* d_in, const int* in_sizes, int n_in,
                              void* d_out, int out_size, void* d_ws, size_t ws_size,
                              hipStream_t stream) {
  const float* x = (const float*)d_in[0];
  const float* y = (const float*)d_in[1];
  float* out = (float*)d_out;

  char* ws = (char*)d_ws;
  float4* x4 = (float4*)ws;                        // 16384 * 16B = 256 KB
  float4* y4 = (float4*)(ws + 262144);             // 256 KB
  float* pot = (float*)(ws + 524288);              // 2 * 65536 floats = 512 KB

  emd_init<<<256, 256, 0, stream>>>(x, y, x4, y4, pot, out);

  // eps schedule: s=8.0 (double), *=0.9 while s>0.01; eps = f32(s)^2; append 0.01^2
  float eps_arr[80];
  int ne = 0;
  double s = 8.0;
  while (s > 0.01) {
    float sf = (float)s;
    eps_arr[ne++] = sf * sf;
    s *= 0.9;
  }
  {
    float bf = 0.01f;
    eps_arr[ne++] = bf * bf;
  }

  const double LOG2E = 1.4426950408889634;
  const double LN2 = 0.6931471805599453;
  const double LOG2048 = 7.624618986159398;  // ln(2048)

  int cur = 0;
  for (int k = 0; k < ne; ++k) {
    float eps = eps_arr[k];
    float c = (float)(LOG2E / (double)eps);
    float nel = (float)(-(double)eps * LN2);
    float elM = (float)((double)eps * LOG2048);
    emd_sweep<false><<<1024, 256, 0, stream>>>(x4, y4, pot + cur * 65536,
                                               pot + (1 - cur) * 65536, out,
                                               c, nel, elM);
    cur ^= 1;
  }

  {
    float eps = eps_arr[ne - 1];
    float c = (float)(LOG2E / (double)eps);
    float nel = (float)(-(double)eps * LN2);
    float elM = (float)((double)eps * LOG2048);
    emd_sweep<true><<<1024, 256, 0, stream>>>(x4, y4, pot + cur * 65536,
                                              nullptr, out, c, nel, elM);
  }
}

// Round 2
// 2169.359 us; speedup vs baseline: 1.4612x; 1.4612x over previous
//
#include <hip/hip_runtime.h>
#include <math.h>

#define NPTS 2048
#define NB 8

// ---------------------------------------------------------------------------
// init: build packed point records (x,y,z, 0.5*|p|^2), zero potentials buf0,
// zero the output scalar. ws is re-poisoned before every timed call.
// ---------------------------------------------------------------------------
__global__ __launch_bounds__(256) void emd_init(const float* __restrict__ x,
                                                const float* __restrict__ y,
                                                float4* __restrict__ x4,
                                                float4* __restrict__ y4,
                                                float* __restrict__ pot0,
                                                float* __restrict__ out) {
  int t = blockIdx.x * blockDim.x + threadIdx.x;  // 0..65535
  if (t < NB * NPTS) {
    float a0 = x[3 * t], a1 = x[3 * t + 1], a2 = x[3 * t + 2];
    x4[t] = make_float4(a0, a1, a2, 0.5f * (a0 * a0 + a1 * a1 + a2 * a2));
    float b0 = y[3 * t], b1 = y[3 * t + 1], b2 = y[3 * t + 2];
    y4[t] = make_float4(b0, b1, b2, 0.5f * (b0 * b0 + b1 * b1 + b2 * b2));
  }
  pot0[t] = 0.0f;  // grid exactly covers 4*NB*NPTS
  if (t == 0) out[0] = 0.0f;
}

// ---------------------------------------------------------------------------
// One Sinkhorn softmin sweep over all 4 matrices.
//   mat 0: rows=x cols=y h=g   -> f_new = 0.5*(f + softmin)
//   mat 1: rows=y cols=x h=f   -> g_new
//   mat 2: rows=x cols=x h=fx  -> fx_new
//   mat 3: rows=y cols=y h=gy  -> gy_new
// 512 blocks x 512 threads: block = (mat, b, 128-row group); 8 waves =
// 2 rowsets x 4 column chunks of 512. Single-round residency (>=2 blocks/CU).
// lane = row; column records broadcast from LDS (wave-uniform address).
// ---------------------------------------------------------------------------
template <bool FINAL>
__global__ __launch_bounds__(512) void emd_sweep(const float4* __restrict__ x4,
                                                 const float4* __restrict__ y4,
                                                 const float* __restrict__ pot_in,
                                                 float* __restrict__ pot_out,
                                                 float* __restrict__ out,
                                                 float c,            // log2e/eps
                                                 float neg_eps_ln2,  // -eps*ln2
                                                 float eps_logM) {   // eps*log(2048)
  __shared__ float4 colpack[NPTS];      // 32 KB
  __shared__ float mbuf[8][64];
  __shared__ float lbuf[8][64];

  int blk = blockIdx.x;                 // 0..511
  int mat = blk >> 7;
  int b = (blk >> 4) & 7;
  int ib2 = blk & 15;
  int tid = threadIdx.x;
  int lane = tid & 63;
  int w = tid >> 6;                     // 0..7
  int rowset = w >> 2;
  int chunk = w & 3;

  const float4* rowp = (mat == 1 || mat == 3) ? y4 : x4;
  const float4* colp = (mat == 0 || mat == 3) ? y4 : x4;
  int hidx = (mat < 2) ? (mat ^ 1) : mat;
  const float* h = pot_in + (hidx * NB + b) * NPTS;
  const float4* colb = colp + b * NPTS;

  // stage columns: (y0,y1,y2, (h_j - 0.5|y_j|^2) * c)
  for (int j = tid; j < NPTS; j += 512) {
    float4 q = colb[j];
    colpack[j] = make_float4(q.x, q.y, q.z, (h[j] - q.w) * c);
  }
  __syncthreads();

  int i = ib2 * 128 + rowset * 64 + lane;
  float4 p = rowp[b * NPTS + i];
  float xs0 = p.x * c, xs1 = p.y * c, xs2 = p.z * c;

  float m = -INFINITY, l = 0.0f;
  int j0 = chunk * 512;
  for (int jt = 0; jt < 512; jt += 16) {
    float s[16];
#pragma unroll
    for (int k = 0; k < 16; ++k) {
      float4 q = colpack[j0 + jt + k];
      s[k] = fmaf(xs0, q.x, fmaf(xs1, q.y, fmaf(xs2, q.z, q.w)));
    }
    // pairwise max tree for ILP
    float t0 = fmaxf(s[0], s[1]), t1 = fmaxf(s[2], s[3]);
    float t2 = fmaxf(s[4], s[5]), t3 = fmaxf(s[6], s[7]);
    float t4 = fmaxf(s[8], s[9]), t5 = fmaxf(s[10], s[11]);
    float t6 = fmaxf(s[12], s[13]), t7 = fmaxf(s[14], s[15]);
    float u0 = fmaxf(t0, t1), u1 = fmaxf(t2, t3);
    float u2 = fmaxf(t4, t5), u3 = fmaxf(t6, t7);
    float mt = fmaxf(fmaxf(u0, u1), fmaxf(u2, u3));
    float mn = fmaxf(m, mt);
    float acc0 = 0.0f, acc1 = 0.0f;
#pragma unroll
    for (int k = 0; k < 16; k += 2) {
      acc0 += __builtin_amdgcn_exp2f(s[k] - mn);
      acc1 += __builtin_amdgcn_exp2f(s[k + 1] - mn);
    }
    l = fmaf(l, __builtin_amdgcn_exp2f(m - mn), acc0 + acc1);
    m = mn;
  }
  mbuf[w][lane] = m;
  lbuf[w][lane] = l;
  __syncthreads();

  if (chunk == 0) {
    int base = rowset * 4;
    float M = mbuf[base][lane];
#pragma unroll
    for (int q = 1; q < 4; ++q) M = fmaxf(M, mbuf[base + q][lane]);
    float L = 0.0f;
#pragma unroll
    for (int q = 0; q < 4; ++q)
      L += lbuf[base + q][lane] * __builtin_amdgcn_exp2f(mbuf[base + q][lane] - M);
    float res = p.w + neg_eps_ln2 * (M + log2f(L)) + eps_logM;
    if (FINAL) {
      float sign = (mat < 2) ? 1.0f : -1.0f;
      float val = sign * res * (1.0f / (float)(NB * NPTS));
#pragma unroll
      for (int off = 32; off; off >>= 1) val += __shfl_xor(val, off);
      if (lane == 0) atomicAdd(out, val);
    } else {
      const float* oldp = pot_in + (mat * NB + b) * NPTS;
      float* outp = pot_out + (mat * NB + b) * NPTS;
      outp[i] = 0.5f * (oldp[i] + res);
    }
  }
}

// ---------------------------------------------------------------------------
extern "C" void kernel_launch(void* const* d_in, const int* in_sizes, int n_in,
                              void* d_out, int out_size, void* d_ws, size_t ws_size,
                              hipStream_t stream) {
  const float* x = (const float*)d_in[0];
  const float* y = (const float*)d_in[1];
  float* out = (float*)d_out;

  char* ws = (char*)d_ws;
  float4* x4 = (float4*)ws;                        // 256 KB
  float4* y4 = (float4*)(ws + 262144);             // 256 KB
  float* pot = (float*)(ws + 524288);              // 2 * 65536 floats

  emd_init<<<256, 256, 0, stream>>>(x, y, x4, y4, pot, out);

  // eps schedule: s=8.0, *=0.9 while s>0.01; eps = f32(s)^2; append 0.01^2
  float eps_arr[80];
  int ne = 0;
  double s = 8.0;
  while (s > 0.01) {
    float sf = (float)s;
    eps_arr[ne++] = sf * sf;
    s *= 0.9;
  }
  {
    float bf = 0.01f;
    eps_arr[ne++] = bf * bf;
  }

  const double LOG2E = 1.4426950408889634;
  const double LN2 = 0.6931471805599453;
  const double LOG2048 = 7.624618986159398;

  int cur = 0;
  for (int k = 0; k < ne; ++k) {
    float eps = eps_arr[k];
    float c = (float)(LOG2E / (double)eps);
    float nel = (float)(-(double)eps * LN2);
    float elM = (float)((double)eps * LOG2048);
    emd_sweep<false><<<512, 512, 0, stream>>>(x4, y4, pot + cur * 65536,
                                              pot + (1 - cur) * 65536, out,
                                              c, nel, elM);
    cur ^= 1;
  }

  {
    float eps = eps_arr[ne - 1];
    float c = (float)(LOG2E / (double)eps);
    float nel = (float)(-(double)eps * LN2);
    float elM = (float)((double)eps * LOG2048);
    emd_sweep<true><<<512, 512, 0, stream>>>(x4, y4, pot + cur * 65536,
                                             nullptr, out, c, nel, elM);
  }
}

// Round 3
// 2107.208 us; speedup vs baseline: 1.5043x; 1.0295x over previous
//
#include <hip/hip_runtime.h>
#include <math.h>

#define NPTS 2048
#define NB 8
#define R 4   // rows per thread

// ---------------------------------------------------------------------------
// init: build packed point records (x,y,z, 0.5*|p|^2), zero potentials buf0,
// zero the output scalar. ws is re-poisoned before every timed call.
// ---------------------------------------------------------------------------
__global__ __launch_bounds__(256) void emd_init(const float* __restrict__ x,
                                                const float* __restrict__ y,
                                                float4* __restrict__ x4,
                                                float4* __restrict__ y4,
                                                float* __restrict__ pot0,
                                                float* __restrict__ out) {
  int t = blockIdx.x * blockDim.x + threadIdx.x;  // 0..65535
  if (t < NB * NPTS) {
    float a0 = x[3 * t], a1 = x[3 * t + 1], a2 = x[3 * t + 2];
    x4[t] = make_float4(a0, a1, a2, 0.5f * (a0 * a0 + a1 * a1 + a2 * a2));
    float b0 = y[3 * t], b1 = y[3 * t + 1], b2 = y[3 * t + 2];
    y4[t] = make_float4(b0, b1, b2, 0.5f * (b0 * b0 + b1 * b1 + b2 * b2));
  }
  pot0[t] = 0.0f;  // grid exactly covers 4*NB*NPTS
  if (t == 0) out[0] = 0.0f;
}

// ---------------------------------------------------------------------------
// One Sinkhorn softmin sweep over all 4 matrices.
//   mat 0: rows=x cols=y h=g   -> f_new = 0.5*(f + softmin)
//   mat 1: rows=y cols=x h=f   -> g_new
//   mat 2: rows=x cols=x h=fx  -> fx_new
//   mat 3: rows=y cols=y h=gy  -> gy_new
// 256 blocks x 512 threads: block = (mat, b, 256-row group). 8 waves = 8
// column chunks of 256. Each thread owns R=4 rows (stride 64): one LDS
// column-tile read is reused for 4 rows -> LDS instr count /4 vs R2 kernel.
// Partial (m,l) per chunk merged through LDS.
// ---------------------------------------------------------------------------
template <bool FINAL>
__global__ __launch_bounds__(512) void emd_sweep(const float4* __restrict__ x4,
                                                 const float4* __restrict__ y4,
                                                 const float* __restrict__ pot_in,
                                                 float* __restrict__ pot_out,
                                                 float* __restrict__ out,
                                                 float c,            // log2e/eps
                                                 float neg_eps_ln2,  // -eps*ln2
                                                 float eps_logM) {   // eps*log(2048)
  __shared__ float4 colpack[NPTS];   // 32 KB
  __shared__ float mbuf[8][256];     // 8 KB
  __shared__ float lbuf[8][256];     // 8 KB

  int blk = blockIdx.x;              // 0..255
  int mat = blk >> 6;
  int b = (blk >> 3) & 7;
  int rg = blk & 7;                  // 256-row group
  int tid = threadIdx.x;
  int lane = tid & 63;
  int w = tid >> 6;                  // 0..7 = column chunk

  const float4* rowp = (mat == 1 || mat == 3) ? y4 : x4;
  const float4* colp = (mat == 0 || mat == 3) ? y4 : x4;
  int hidx = (mat < 2) ? (mat ^ 1) : mat;
  const float* h = pot_in + (hidx * NB + b) * NPTS;
  const float4* colb = colp + b * NPTS;

  // stage columns: (y0,y1,y2, (h_j - 0.5|y_j|^2) * c)
  for (int j = tid; j < NPTS; j += 512) {
    float4 q = colb[j];
    colpack[j] = make_float4(q.x, q.y, q.z, (h[j] - q.w) * c);
  }
  __syncthreads();

  int rowbase = rg * 256;
  const float4* rowb = rowp + b * NPTS + rowbase;

  float xs[R][3];
  float m[R], l[R];
#pragma unroll
  for (int r = 0; r < R; ++r) {
    float4 p = rowb[r * 64 + lane];
    xs[r][0] = p.x * c;
    xs[r][1] = p.y * c;
    xs[r][2] = p.z * c;
    m[r] = -INFINITY;
    l[r] = 0.0f;
  }

  int j0 = w * 256;
  for (int jt = 0; jt < 256; jt += 8) {
    float4 q[8];
#pragma unroll
    for (int k = 0; k < 8; ++k) q[k] = colpack[j0 + jt + k];
#pragma unroll
    for (int r = 0; r < R; ++r) {
      float s[8];
#pragma unroll
      for (int k = 0; k < 8; ++k)
        s[k] = fmaf(xs[r][0], q[k].x,
                    fmaf(xs[r][1], q[k].y, fmaf(xs[r][2], q[k].z, q[k].w)));
      float t0 = fmaxf(s[0], s[1]), t1 = fmaxf(s[2], s[3]);
      float t2 = fmaxf(s[4], s[5]), t3 = fmaxf(s[6], s[7]);
      float mt = fmaxf(fmaxf(t0, t1), fmaxf(t2, t3));
      float mn = fmaxf(m[r], mt);
      float acc0 = 0.0f, acc1 = 0.0f;
#pragma unroll
      for (int k = 0; k < 8; k += 2) {
        acc0 += __builtin_amdgcn_exp2f(s[k] - mn);
        acc1 += __builtin_amdgcn_exp2f(s[k + 1] - mn);
      }
      l[r] = fmaf(l[r], __builtin_amdgcn_exp2f(m[r] - mn), acc0 + acc1);
      m[r] = mn;
    }
  }

#pragma unroll
  for (int r = 0; r < R; ++r) {
    mbuf[w][r * 64 + lane] = m[r];
    lbuf[w][r * 64 + lane] = l[r];
  }
  __syncthreads();

  if (w < 4) {
    int row = w * 64 + lane;  // 0..255
    float M = mbuf[0][row];
#pragma unroll
    for (int q = 1; q < 8; ++q) M = fmaxf(M, mbuf[q][row]);
    float L = 0.0f;
#pragma unroll
    for (int q = 0; q < 8; ++q)
      L += lbuf[q][row] * __builtin_amdgcn_exp2f(mbuf[q][row] - M);
    float pw = rowb[row].w;
    float res = pw + neg_eps_ln2 * (M + log2f(L)) + eps_logM;
    if (FINAL) {
      float sign = (mat < 2) ? 1.0f : -1.0f;
      float val = sign * res * (1.0f / (float)(NB * NPTS));
#pragma unroll
      for (int off = 32; off; off >>= 1) val += __shfl_xor(val, off);
      if (lane == 0) atomicAdd(out, val);
    } else {
      const float* oldp = pot_in + (mat * NB + b) * NPTS + rowbase;
      float* outp = pot_out + (mat * NB + b) * NPTS + rowbase;
      outp[row] = 0.5f * (oldp[row] + res);
    }
  }
}

// ---------------------------------------------------------------------------
extern "C" void kernel_launch(void* const* d_in, const int* in_sizes, int n_in,
                              void* d_out, int out_size, void* d_ws, size_t ws_size,
                              hipStream_t stream) {
  const float* x = (const float*)d_in[0];
  const float* y = (const float*)d_in[1];
  float* out = (float*)d_out;

  char* ws = (char*)d_ws;
  float4* x4 = (float4*)ws;                        // 256 KB
  float4* y4 = (float4*)(ws + 262144);             // 256 KB
  float* pot = (float*)(ws + 524288);              // 2 * 65536 floats

  emd_init<<<256, 256, 0, stream>>>(x, y, x4, y4, pot, out);

  // eps schedule: s=8.0, *=0.9 while s>0.01; eps = f32(s)^2; append 0.01^2
  float eps_arr[80];
  int ne = 0;
  double s = 8.0;
  while (s > 0.01) {
    float sf = (float)s;
    eps_arr[ne++] = sf * sf;
    s *= 0.9;
  }
  {
    float bf = 0.01f;
    eps_arr[ne++] = bf * bf;
  }

  const double LOG2E = 1.4426950408889634;
  const double LN2 = 0.6931471805599453;
  const double LOG2048 = 7.624618986159398;

  int cur = 0;
  for (int k = 0; k < ne; ++k) {
    float eps = eps_arr[k];
    float c = (float)(LOG2E / (double)eps);
    float nel = (float)(-(double)eps * LN2);
    float elM = (float)((double)eps * LOG2048);
    emd_sweep<false><<<256, 512, 0, stream>>>(x4, y4, pot + cur * 65536,
                                              pot + (1 - cur) * 65536, out,
                                              c, nel, elM);
    cur ^= 1;
  }

  {
    float eps = eps_arr[ne - 1];
    float c = (float)(LOG2E / (double)eps);
    float nel = (float)(-(double)eps * LN2);
    float elM = (float)((double)eps * LOG2048);
    emd_sweep<true><<<256, 512, 0, stream>>>(x4, y4, pot + cur * 65536,
                                             nullptr, out, c, nel, elM);
  }
}

// Round 4
// 1971.506 us; speedup vs baseline: 1.6079x; 1.0688x over previous
//
#include <hip/hip_runtime.h>
#include <math.h>

#define NPTS 2048
#define NB 8
#define R 4        // rows per thread
#define NW 16      // waves per block = column chunks
#define CCH 128    // columns per chunk (NPTS / NW)

// ---------------------------------------------------------------------------
// init: build packed point records (x,y,z, 0.5*|p|^2), zero potentials buf0,
// zero the output scalar. ws is re-poisoned before every timed call.
// ---------------------------------------------------------------------------
__global__ __launch_bounds__(256) void emd_init(const float* __restrict__ x,
                                                const float* __restrict__ y,
                                                float4* __restrict__ x4,
                                                float4* __restrict__ y4,
                                                float* __restrict__ pot0,
                                                float* __restrict__ out) {
  int t = blockIdx.x * blockDim.x + threadIdx.x;  // 0..65535
  if (t < NB * NPTS) {
    float a0 = x[3 * t], a1 = x[3 * t + 1], a2 = x[3 * t + 2];
    x4[t] = make_float4(a0, a1, a2, 0.5f * (a0 * a0 + a1 * a1 + a2 * a2));
    float b0 = y[3 * t], b1 = y[3 * t + 1], b2 = y[3 * t + 2];
    y4[t] = make_float4(b0, b1, b2, 0.5f * (b0 * b0 + b1 * b1 + b2 * b2));
  }
  pot0[t] = 0.0f;  // grid exactly covers 4*NB*NPTS
  if (t == 0) out[0] = 0.0f;
}

// ---------------------------------------------------------------------------
// One Sinkhorn softmin sweep over all 4 matrices.
//   mat 0: rows=x cols=y h=g   -> f_new = 0.5*(f + softmin)
//   mat 1: rows=y cols=x h=f   -> g_new
//   mat 2: rows=x cols=x h=fx  -> fx_new
//   mat 3: rows=y cols=y h=gy  -> gy_new
// 256 blocks x 1024 threads: block = (mat, b, 256-row group). 16 waves = 16
// column chunks of 128 cols; each thread owns R=4 rows (stride 64). One LDS
// broadcast read of a column record is reused 4x. 4 waves/SIMD resident.
// Merge buffers are UNIONED with colpack (colpack dead after main loop) so
// LDS stays 32 KB.
// ---------------------------------------------------------------------------
template <bool FINAL>
__global__ __launch_bounds__(1024) void emd_sweep(const float4* __restrict__ x4,
                                                  const float4* __restrict__ y4,
                                                  const float* __restrict__ pot_in,
                                                  float* __restrict__ pot_out,
                                                  float* __restrict__ out,
                                                  float c,            // log2e/eps
                                                  float neg_eps_ln2,  // -eps*ln2
                                                  float eps_logM) {   // eps*log(2048)
  __shared__ union {
    float4 colpack[NPTS];          // 32 KB (staging + main loop)
    struct {
      float m[NW][256];            // 16 KB (merge phase)
      float l[NW][256];            // 16 KB
    } mg;
  } sh;

  int blk = blockIdx.x;            // 0..255
  int mat = blk >> 6;
  int b = (blk >> 3) & 7;
  int rg = blk & 7;                // 256-row group
  int tid = threadIdx.x;
  int lane = tid & 63;
  int w = tid >> 6;                // 0..15 = column chunk

  const float4* rowp = (mat == 1 || mat == 3) ? y4 : x4;
  const float4* colp = (mat == 0 || mat == 3) ? y4 : x4;
  int hidx = (mat < 2) ? (mat ^ 1) : mat;
  const float* h = pot_in + (hidx * NB + b) * NPTS;
  const float4* colb = colp + b * NPTS;

  // stage columns: (y0,y1,y2, (h_j - 0.5|y_j|^2) * c)
  for (int j = tid; j < NPTS; j += 1024) {
    float4 q = colb[j];
    sh.colpack[j] = make_float4(q.x, q.y, q.z, (h[j] - q.w) * c);
  }
  __syncthreads();

  int rowbase = rg * 256;
  const float4* rowb = rowp + b * NPTS + rowbase;

  float xs[R][3];
  float m[R], l[R];
#pragma unroll
  for (int r = 0; r < R; ++r) {
    float4 p = rowb[r * 64 + lane];
    xs[r][0] = p.x * c;
    xs[r][1] = p.y * c;
    xs[r][2] = p.z * c;
    m[r] = -INFINITY;
    l[r] = 0.0f;
  }

  int j0 = w * CCH;
  for (int jt = 0; jt < CCH; jt += 8) {
    float4 q[8];
#pragma unroll
    for (int k = 0; k < 8; ++k) q[k] = sh.colpack[j0 + jt + k];
#pragma unroll
    for (int r = 0; r < R; ++r) {
      float s[8];
#pragma unroll
      for (int k = 0; k < 8; ++k)
        s[k] = fmaf(xs[r][0], q[k].x,
                    fmaf(xs[r][1], q[k].y, fmaf(xs[r][2], q[k].z, q[k].w)));
      float t0 = fmaxf(s[0], s[1]), t1 = fmaxf(s[2], s[3]);
      float t2 = fmaxf(s[4], s[5]), t3 = fmaxf(s[6], s[7]);
      float mt = fmaxf(fmaxf(t0, t1), fmaxf(t2, t3));
      float mn = fmaxf(m[r], mt);
      float acc0 = 0.0f, acc1 = 0.0f;
#pragma unroll
      for (int k = 0; k < 8; k += 2) {
        acc0 += __builtin_amdgcn_exp2f(s[k] - mn);
        acc1 += __builtin_amdgcn_exp2f(s[k + 1] - mn);
      }
      l[r] = fmaf(l[r], __builtin_amdgcn_exp2f(m[r] - mn), acc0 + acc1);
      m[r] = mn;
    }
  }

  __syncthreads();  // everyone done reading colpack; safe to overwrite (union)
#pragma unroll
  for (int r = 0; r < R; ++r) {
    sh.mg.m[w][r * 64 + lane] = m[r];
    sh.mg.l[w][r * 64 + lane] = l[r];
  }
  __syncthreads();

  if (w < 4) {
    int row = w * 64 + lane;  // 0..255
    float M = sh.mg.m[0][row];
#pragma unroll
    for (int q = 1; q < NW; ++q) M = fmaxf(M, sh.mg.m[q][row]);
    float L = 0.0f;
#pragma unroll
    for (int q = 0; q < NW; ++q)
      L += sh.mg.l[q][row] * __builtin_amdgcn_exp2f(sh.mg.m[q][row] - M);
    float pw = rowb[row].w;
    float res = pw + neg_eps_ln2 * (M + log2f(L)) + eps_logM;
    if (FINAL) {
      float sign = (mat < 2) ? 1.0f : -1.0f;
      float val = sign * res * (1.0f / (float)(NB * NPTS));
#pragma unroll
      for (int off = 32; off; off >>= 1) val += __shfl_xor(val, off);
      if (lane == 0) atomicAdd(out, val);
    } else {
      const float* oldp = pot_in + (mat * NB + b) * NPTS + rowbase;
      float* outp = pot_out + (mat * NB + b) * NPTS + rowbase;
      outp[row] = 0.5f * (oldp[row] + res);
    }
  }
}

// ---------------------------------------------------------------------------
extern "C" void kernel_launch(void* const* d_in, const int* in_sizes, int n_in,
                              void* d_out, int out_size, void* d_ws, size_t ws_size,
                              hipStream_t stream) {
  const float* x = (const float*)d_in[0];
  const float* y = (const float*)d_in[1];
  float* out = (float*)d_out;

  char* ws = (char*)d_ws;
  float4* x4 = (float4*)ws;                        // 256 KB
  float4* y4 = (float4*)(ws + 262144);             // 256 KB
  float* pot = (float*)(ws + 524288);              // 2 * 65536 floats

  emd_init<<<256, 256, 0, stream>>>(x, y, x4, y4, pot, out);

  // eps schedule: s=8.0, *=0.9 while s>0.01; eps = f32(s)^2; append 0.01^2
  float eps_arr[80];
  int ne = 0;
  double s = 8.0;
  while (s > 0.01) {
    float sf = (float)s;
    eps_arr[ne++] = sf * sf;
    s *= 0.9;
  }
  {
    float bf = 0.01f;
    eps_arr[ne++] = bf * bf;
  }

  const double LOG2E = 1.4426950408889634;
  const double LN2 = 0.6931471805599453;
  const double LOG2048 = 7.624618986159398;

  int cur = 0;
  for (int k = 0; k < ne; ++k) {
    float eps = eps_arr[k];
    float c = (float)(LOG2E / (double)eps);
    float nel = (float)(-(double)eps * LN2);
    float elM = (float)((double)eps * LOG2048);
    emd_sweep<false><<<256, 1024, 0, stream>>>(x4, y4, pot + cur * 65536,
                                               pot + (1 - cur) * 65536, out,
                                               c, nel, elM);
    cur ^= 1;
  }

  {
    float eps = eps_arr[ne - 1];
    float c = (float)(LOG2E / (double)eps);
    float nel = (float)(-(double)eps * LN2);
    float elM = (float)((double)eps * LOG2048);
    emd_sweep<true><<<256, 1024, 0, stream>>>(x4, y4, pot + cur * 65536,
                                              nullptr, out, c, nel, elM);
  }
}